// Round 1
// baseline (950.091 us; speedup 1.0000x reference)
//
#include <hip/hip_runtime.h>

#define NROWS 262144
#define NUM_CODES 1024
#define CODE_DIM 64
#define TK 128  // codes per LDS tile: 128*64*4 = 32 KiB

// Pre-kernel: half squared norms of each code -> d_ws[0..1023]
__global__ __launch_bounds__(256) void vq_csq_kernel(const float* __restrict__ codebook,
                                                     float* __restrict__ half_csq) {
    int k = blockIdx.x * 256 + threadIdx.x;
    if (k >= NUM_CODES) return;
    const float4* row = (const float4*)(codebook + (size_t)k * CODE_DIM);
    float s0 = 0.f, s1 = 0.f, s2 = 0.f, s3 = 0.f;
#pragma unroll
    for (int j = 0; j < CODE_DIM / 4; ++j) {
        float4 c = row[j];
        s0 += c.x * c.x;
        s1 += c.y * c.y;
        s2 += c.z * c.z;
        s3 += c.w * c.w;
    }
    half_csq[k] = 0.5f * ((s0 + s1) + (s2 + s3));
}

// Main kernel: one input row per thread; codebook tiled through LDS.
// argmin(dist) == argmax(x.c - 0.5*||c||^2); strict '>' keeps the first
// (lowest) index on ties, matching jnp.argmin's first-occurrence rule.
__global__ __launch_bounds__(256) void vq_main_kernel(const float* __restrict__ inputs,
                                                      const float* __restrict__ codebook,
                                                      const float* __restrict__ half_csq,
                                                      float* __restrict__ out) {
    __shared__ float tile[TK][CODE_DIM];
    __shared__ float hcsq[TK];

    const int row = blockIdx.x * 256 + threadIdx.x;

    // Load this thread's input row into registers (64 VGPRs).
    float4 x[CODE_DIM / 4];
    {
        const float4* xr = (const float4*)(inputs + (size_t)row * CODE_DIM);
#pragma unroll
        for (int j = 0; j < CODE_DIM / 4; ++j) x[j] = xr[j];
    }

    float best = -INFINITY;
    int bidx = 0;

    for (int k0 = 0; k0 < NUM_CODES; k0 += TK) {
        __syncthreads();
        // Cooperative staging: TK*CODE_DIM/4 = 2048 float4, 256 threads -> 8 each.
        {
            const float4* src = (const float4*)(codebook + (size_t)k0 * CODE_DIM);
            float4* dst = (float4*)&tile[0][0];
#pragma unroll
            for (int i = 0; i < (TK * CODE_DIM / 4) / 256; ++i)
                dst[threadIdx.x + i * 256] = src[threadIdx.x + i * 256];
            if (threadIdx.x < TK) hcsq[threadIdx.x] = half_csq[k0 + threadIdx.x];
        }
        __syncthreads();

        for (int k = 0; k < TK; ++k) {
            const float4* crow = (const float4*)&tile[k][0];
            // 4 independent accumulator chains for FMA ILP.
            float s0 = -hcsq[k], s1 = 0.f, s2 = 0.f, s3 = 0.f;
#pragma unroll
            for (int j = 0; j < CODE_DIM / 4; ++j) {
                float4 c = crow[j];  // same addr all lanes: LDS broadcast, no conflict
                s0 += x[j].x * c.x;
                s1 += x[j].y * c.y;
                s2 += x[j].z * c.z;
                s3 += x[j].w * c.w;
            }
            float s = (s0 + s1) + (s2 + s3);
            if (s > best) { best = s; bidx = k0 + k; }
        }
    }

    // Gather winning code (codebook is 256 KiB -> L2-resident) and write out.
    const float4* brow = (const float4*)(codebook + (size_t)bidx * CODE_DIM);
    float4* orow = (float4*)(out + (size_t)row * CODE_DIM);
#pragma unroll
    for (int j = 0; j < CODE_DIM / 4; ++j) orow[j] = brow[j];
}

extern "C" void kernel_launch(void* const* d_in, const int* in_sizes, int n_in,
                              void* d_out, int out_size, void* d_ws, size_t ws_size,
                              hipStream_t stream) {
    const float* inputs = (const float*)d_in[0];    // [262144, 64] fp32
    const float* codebook = (const float*)d_in[1];  // [1024, 64] fp32
    float* out = (float*)d_out;                     // [262144, 64] fp32
    float* half_csq = (float*)d_ws;                 // 1024 floats scratch

    vq_csq_kernel<<<NUM_CODES / 256, 256, 0, stream>>>(codebook, half_csq);
    vq_main_kernel<<<NROWS / 256, 256, 0, stream>>>(inputs, codebook, half_csq, out);
}

// Round 2
// 642.777 us; speedup vs baseline: 1.4781x; 1.4781x over previous
//
#include <hip/hip_runtime.h>

#define NROWS   262144
#define NCODES  1024
#define DIM     64
#define MARGIN  0.06f
#define LIST_CAP 65536u

typedef __attribute__((ext_vector_type(8))) short bf16x8;   // 8 bf16 (4 VGPRs)
typedef __attribute__((ext_vector_type(4))) float f32x4;

// RNE float -> bf16 (matches HW cvt); bf16 -> float by shift.
__device__ __forceinline__ short f2bf(float f) {
    unsigned u = __builtin_bit_cast(unsigned, f);
    unsigned r = (u + 0x7fffu + ((u >> 16) & 1u)) >> 16;
    return (short)r;
}
__device__ __forceinline__ float bf2f(short s) {
    unsigned u = ((unsigned)(unsigned short)s) << 16;
    return __builtin_bit_cast(float, u);
}

// ---------------------------------------------------------------------------
// Prep: split codebook into bf16 hi/lo, half squared norms, zero flag counter.
// ---------------------------------------------------------------------------
__global__ __launch_bounds__(256) void vq_prep(const float* __restrict__ cb,
                                               float* __restrict__ hcsq,
                                               short* __restrict__ Ch,
                                               short* __restrict__ Cl,
                                               unsigned* __restrict__ cnt) {
    int k = blockIdx.x * 256 + threadIdx.x;
    if (k == 0) *cnt = 0u;
    if (k >= NCODES) return;
    const float* row = cb + (size_t)k * DIM;
    float s = 0.f;
#pragma unroll
    for (int j = 0; j < DIM; ++j) {
        float c = row[j];
        s += c * c;
        short h = f2bf(c);
        Ch[(size_t)k * DIM + j] = h;
        Cl[(size_t)k * DIM + j] = f2bf(c - bf2f(h));
    }
    hcsq[k] = 0.5f * s;
}

// ---------------------------------------------------------------------------
// Main: MFMA split-bf16 scores + fused top-2 argmax, gather, flag near-ties.
// Wave = 32 rows (2 m-tiles of 16) x all 1024 codes. Block = 4 waves = 128 rows.
// ---------------------------------------------------------------------------
__global__ __launch_bounds__(256, 3) void vq_mfma(const float* __restrict__ inputs,
                                                  const float* __restrict__ cb,
                                                  const float* __restrict__ hcsq,
                                                  const short* __restrict__ Ch,
                                                  const short* __restrict__ Cl,
                                                  float* __restrict__ out,
                                                  unsigned* __restrict__ cnt,
                                                  unsigned* __restrict__ list) {
    const int lane = threadIdx.x & 63;
    const int wave = threadIdx.x >> 6;
    const int m = lane & 15;   // A row-in-tile / B code-in-tile / D col
    const int q = lane >> 4;   // k-quad
    const size_t rowbase = (size_t)blockIdx.x * 128 + (size_t)wave * 32;

    // A fragments in registers for the whole kernel: [m-tile][k-step], hi+lo.
    bf16x8 ah[2][2], al[2][2];
#pragma unroll
    for (int t = 0; t < 2; ++t) {
        const float* px = inputs + (rowbase + t * 16 + m) * DIM;
#pragma unroll
        for (int s = 0; s < 2; ++s) {
            const float4* p = (const float4*)(px + q * 8 + s * 32);
            float4 v0 = p[0], v1 = p[1];
            float v[8] = {v0.x, v0.y, v0.z, v0.w, v1.x, v1.y, v1.z, v1.w};
            union { bf16x8 f; short s16[8]; } uh, ul;
#pragma unroll
            for (int j = 0; j < 8; ++j) {
                short h = f2bf(v[j]);
                uh.s16[j] = h;
                ul.s16[j] = f2bf(v[j] - bf2f(h));
            }
            ah[t][s] = uh.f;
            al[t][s] = ul.f;
        }
    }

    float best[2][4], second[2][4];
    int bidx[2][4];
#pragma unroll
    for (int t = 0; t < 2; ++t)
#pragma unroll
        for (int r = 0; r < 4; ++r) {
            best[t][r] = -INFINITY;
            second[t][r] = -INFINITY;
            bidx[t][r] = 0;
        }

    for (int ct = 0; ct < NCODES / 16; ++ct) {
        // B fragments straight from L2-resident bf16 codebook (no LDS).
        const short* pc = Ch + ((size_t)ct * 16 + m) * DIM + q * 8;
        const short* pl = Cl + ((size_t)ct * 16 + m) * DIM + q * 8;
        bf16x8 bh0 = *(const bf16x8*)pc;
        bf16x8 bh1 = *(const bf16x8*)(pc + 32);
        bf16x8 bl0 = *(const bf16x8*)pl;
        bf16x8 bl1 = *(const bf16x8*)(pl + 32);
        float hc = hcsq[ct * 16 + m];

        // hi*hi chains (2 deps) and correction chains (4 deps) per m-tile.
        f32x4 h0 = {0.f, 0.f, 0.f, 0.f}, h1 = {0.f, 0.f, 0.f, 0.f};
        f32x4 c0 = {0.f, 0.f, 0.f, 0.f}, c1 = {0.f, 0.f, 0.f, 0.f};
        h0 = __builtin_amdgcn_mfma_f32_16x16x32_bf16(ah[0][0], bh0, h0, 0, 0, 0);
        h1 = __builtin_amdgcn_mfma_f32_16x16x32_bf16(ah[1][0], bh0, h1, 0, 0, 0);
        c0 = __builtin_amdgcn_mfma_f32_16x16x32_bf16(ah[0][0], bl0, c0, 0, 0, 0);
        c1 = __builtin_amdgcn_mfma_f32_16x16x32_bf16(ah[1][0], bl0, c1, 0, 0, 0);
        h0 = __builtin_amdgcn_mfma_f32_16x16x32_bf16(ah[0][1], bh1, h0, 0, 0, 0);
        h1 = __builtin_amdgcn_mfma_f32_16x16x32_bf16(ah[1][1], bh1, h1, 0, 0, 0);
        c0 = __builtin_amdgcn_mfma_f32_16x16x32_bf16(ah[0][1], bl1, c0, 0, 0, 0);
        c1 = __builtin_amdgcn_mfma_f32_16x16x32_bf16(ah[1][1], bl1, c1, 0, 0, 0);
        c0 = __builtin_amdgcn_mfma_f32_16x16x32_bf16(al[0][0], bh0, c0, 0, 0, 0);
        c1 = __builtin_amdgcn_mfma_f32_16x16x32_bf16(al[1][0], bh0, c1, 0, 0, 0);
        c0 = __builtin_amdgcn_mfma_f32_16x16x32_bf16(al[0][1], bh1, c0, 0, 0, 0);
        c1 = __builtin_amdgcn_mfma_f32_16x16x32_bf16(al[1][1], bh1, c1, 0, 0, 0);

        int n = ct * 16 + m;
#pragma unroll
        for (int r = 0; r < 4; ++r) {
            float s0 = (h0[r] + c0[r]) - hc;
            second[0][r] = fmaxf(second[0][r], fminf(s0, best[0][r]));
            if (s0 > best[0][r]) { best[0][r] = s0; bidx[0][r] = n; }
            float s1 = (h1[r] + c1[r]) - hc;
            second[1][r] = fmaxf(second[1][r], fminf(s1, best[1][r]));
            if (s1 > best[1][r]) { best[1][r] = s1; bidx[1][r] = n; }
        }
    }

    // Cross-lane top-2 merge within each 16-lane group; min-index tie-break
    // (matches jnp.argmin first-occurrence). Then gather + write + flag.
#pragma unroll
    for (int t = 0; t < 2; ++t)
#pragma unroll
        for (int r = 0; r < 4; ++r) {
            float b = best[t][r], sc = second[t][r];
            int bi = bidx[t][r];
#pragma unroll
            for (int off = 1; off < 16; off <<= 1) {
                float ob = __shfl_xor(b, off);
                float os = __shfl_xor(sc, off);
                int oi = __shfl_xor(bi, off);
                sc = fmaxf(fmaxf(sc, os), fminf(b, ob));
                if (ob > b || (ob == b && oi < bi)) { b = ob; bi = oi; }
            }
            size_t row = rowbase + t * 16 + q * 4 + r;
            const float4* src = (const float4*)(cb + (size_t)bi * DIM);
            float4* dst = (float4*)(out + row * DIM);
            dst[m] = src[m];
            if (m == 0 && (b - sc) < MARGIN) {
                unsigned pos = atomicAdd(cnt, 1u);
                if (pos < LIST_CAP) list[pos] = (unsigned)row;
            }
        }
}

// ---------------------------------------------------------------------------
// Rescue: exact fp32 argmax (round-1 formula, absmax 0) for flagged rows.
// One wave per flagged row; lanes split codes; min-index tie-break.
// ---------------------------------------------------------------------------
__global__ __launch_bounds__(256) void vq_rescue(const float* __restrict__ inputs,
                                                 const float* __restrict__ cb,
                                                 const float* __restrict__ hcsq,
                                                 const unsigned* __restrict__ cnt,
                                                 const unsigned* __restrict__ list,
                                                 float* __restrict__ out) {
    unsigned n = *cnt;
    if (n > LIST_CAP) n = LIST_CAP;
    const int lane = threadIdx.x & 63;
    unsigned gw = blockIdx.x * 4u + (threadIdx.x >> 6);
    for (unsigned e = gw; e < n; e += gridDim.x * 4u) {
        unsigned row = list[e];
        const float4* xr = (const float4*)(inputs + (size_t)row * DIM);
        float4 x[16];
#pragma unroll
        for (int j = 0; j < 16; ++j) x[j] = xr[j];
        float best = -INFINITY;
        int bi = 0;
        for (int i = 0; i < NCODES / 64; ++i) {
            int c = i * 64 + lane;
            const float4* cr = (const float4*)(cb + (size_t)c * DIM);
            float s0 = -hcsq[c], s1 = 0.f, s2 = 0.f, s3 = 0.f;
#pragma unroll
            for (int j = 0; j < 16; ++j) {
                float4 cv = cr[j];
                s0 += x[j].x * cv.x;
                s1 += x[j].y * cv.y;
                s2 += x[j].z * cv.z;
                s3 += x[j].w * cv.w;
            }
            float s = (s0 + s1) + (s2 + s3);
            if (s > best) { best = s; bi = c; }
        }
#pragma unroll
        for (int off = 1; off < 64; off <<= 1) {
            float ob = __shfl_xor(best, off);
            int oi = __shfl_xor(bi, off);
            if (ob > best || (ob == best && oi < bi)) { best = ob; bi = oi; }
        }
        out[(size_t)row * DIM + lane] = cb[(size_t)bi * DIM + lane];
    }
}

extern "C" void kernel_launch(void* const* d_in, const int* in_sizes, int n_in,
                              void* d_out, int out_size, void* d_ws, size_t ws_size,
                              hipStream_t stream) {
    const float* inputs = (const float*)d_in[0];    // [262144, 64] fp32
    const float* cb = (const float*)d_in[1];        // [1024, 64] fp32
    float* out = (float*)d_out;

    // ws layout: hcsq f32[1024] | Ch bf16[1024*64] | Cl bf16[1024*64] | cnt | list
    char* ws = (char*)d_ws;
    float* hcsq = (float*)ws;                                   //   4 KiB
    short* Ch = (short*)(ws + 4096);                            // 128 KiB
    short* Cl = (short*)(ws + 4096 + 131072);                   // 128 KiB
    unsigned* cnt = (unsigned*)(ws + 4096 + 262144);            // 256 B slot
    unsigned* list = (unsigned*)(ws + 4096 + 262144 + 256);     // 256 KiB

    vq_prep<<<NCODES / 256, 256, 0, stream>>>(cb, hcsq, Ch, Cl, cnt);
    vq_mfma<<<NROWS / 128, 256, 0, stream>>>(inputs, cb, hcsq, Ch, Cl, out, cnt, list);
    vq_rescue<<<256, 256, 0, stream>>>(inputs, cb, hcsq, cnt, list, out);
}

// Round 3
// 572.744 us; speedup vs baseline: 1.6588x; 1.1223x over previous
//
#include <hip/hip_runtime.h>

#define NROWS   262144
#define NCODES  1024
#define DIM     64
#define MARGIN  0.06f
#define LIST_CAP 65536u

typedef __attribute__((ext_vector_type(8))) short bf16x8;   // 8 bf16 (4 VGPRs)
typedef __attribute__((ext_vector_type(4))) float f32x4;

// RNE float -> bf16; bf16 -> float by shift.
__device__ __forceinline__ short f2bf(float f) {
    unsigned u = __builtin_bit_cast(unsigned, f);
    unsigned r = (u + 0x7fffu + ((u >> 16) & 1u)) >> 16;
    return (short)r;
}
__device__ __forceinline__ float bf2f(short s) {
    unsigned u = ((unsigned)(unsigned short)s) << 16;
    return __builtin_bit_cast(float, u);
}

#define MFMA(acc, a, b) acc = __builtin_amdgcn_mfma_f32_16x16x32_bf16(a, b, acc, 0, 0, 0)

// ---------------------------------------------------------------------------
// Prep: split codebook into bf16 hi/lo (vectorized), half norms, zero counter.
// ---------------------------------------------------------------------------
__global__ __launch_bounds__(256) void vq_prep(const float* __restrict__ cb,
                                               float* __restrict__ hcsq,
                                               short* __restrict__ Ch,
                                               short* __restrict__ Cl,
                                               unsigned* __restrict__ cnt) {
    int k = blockIdx.x * 256 + threadIdx.x;
    if (k == 0) *cnt = 0u;
    if (k >= NCODES) return;
    const float4* row = (const float4*)(cb + (size_t)k * DIM);
    bf16x8* ch = (bf16x8*)(Ch + (size_t)k * DIM);
    bf16x8* cl = (bf16x8*)(Cl + (size_t)k * DIM);
    float s = 0.f;
#pragma unroll
    for (int i = 0; i < 8; ++i) {
        float4 a = row[2 * i], b = row[2 * i + 1];
        float v[8] = {a.x, a.y, a.z, a.w, b.x, b.y, b.z, b.w};
        union { bf16x8 f; short e[8]; } uh, ul;
#pragma unroll
        for (int j = 0; j < 8; ++j) {
            s += v[j] * v[j];
            short h = f2bf(v[j]);
            uh.e[j] = h;
            ul.e[j] = f2bf(v[j] - bf2f(h));
        }
        ch[i] = uh.f;
        cl[i] = ul.f;
    }
    hcsq[k] = 0.5f * s;
}

// ---------------------------------------------------------------------------
// Main: MFMA split-bf16 scores, register-double-buffered B, fused top-2.
// Wave = 32 rows x all 1024 codes, 2 code-tiles (32 codes) per iteration.
// ---------------------------------------------------------------------------
__global__ __launch_bounds__(256) void vq_mfma_k(const float* __restrict__ inputs,
                                                 const float* __restrict__ cb,
                                                 const float* __restrict__ hcsq,
                                                 const short* __restrict__ Ch,
                                                 const short* __restrict__ Cl,
                                                 float* __restrict__ out,
                                                 unsigned* __restrict__ cnt,
                                                 unsigned* __restrict__ list) {
    const int lane = threadIdx.x & 63;
    const int wave = threadIdx.x >> 6;
    const int m = lane & 15;   // A row-in-tile / B code-in-tile / D col
    const int q = lane >> 4;   // k-quad
    const size_t rowbase = (size_t)blockIdx.x * 128 + (size_t)wave * 32;

    // A fragments in registers for the whole kernel (validated layout, r2).
    bf16x8 ah[2][2], al[2][2];
#pragma unroll
    for (int t = 0; t < 2; ++t) {
        const float* px = inputs + (rowbase + t * 16 + m) * DIM;
#pragma unroll
        for (int s = 0; s < 2; ++s) {
            const float4* p = (const float4*)(px + q * 8 + s * 32);
            float4 v0 = p[0], v1 = p[1];
            float v[8] = {v0.x, v0.y, v0.z, v0.w, v1.x, v1.y, v1.z, v1.w};
            union { bf16x8 f; short e[8]; } uh, ul;
#pragma unroll
            for (int j = 0; j < 8; ++j) {
                short h = f2bf(v[j]);
                uh.e[j] = h;
                ul.e[j] = f2bf(v[j] - bf2f(h));
            }
            ah[t][s] = uh.f;
            al[t][s] = ul.f;
        }
    }

    float best[2][4], second[2][4];
    int bidx[2][4];
#pragma unroll
    for (int t = 0; t < 2; ++t)
#pragma unroll
        for (int r = 0; r < 4; ++r) {
            best[t][r] = -INFINITY;
            second[t][r] = -INFINITY;
            bidx[t][r] = 0;
        }

    // Per-lane B base pointers; tile stride = 16 codes * 64 = 1024 shorts.
    const short* baseCh = Ch + (size_t)m * DIM + q * 8;
    const short* baseCl = Cl + (size_t)m * DIM + q * 8;

    // Register double-buffer: tiles ct (buf0) and ct+1 (buf1) in flight.
    bf16x8 b0h0 = *(const bf16x8*)(baseCh);
    bf16x8 b0h1 = *(const bf16x8*)(baseCh + 32);
    bf16x8 b0l0 = *(const bf16x8*)(baseCl);
    bf16x8 b0l1 = *(const bf16x8*)(baseCl + 32);
    float hc0 = hcsq[m];
    bf16x8 b1h0 = *(const bf16x8*)(baseCh + 1024);
    bf16x8 b1h1 = *(const bf16x8*)(baseCh + 1024 + 32);
    bf16x8 b1l0 = *(const bf16x8*)(baseCl + 1024);
    bf16x8 b1l1 = *(const bf16x8*)(baseCl + 1024 + 32);
    float hc1 = hcsq[16 + m];

#define EPILOGUE(H0, C0, H1, C1, HC, TILE)                                      \
    {                                                                           \
        int n = (TILE) * 16 + m;                                                \
        _Pragma("unroll") for (int r = 0; r < 4; ++r) {                         \
            float s0 = (H0[r] + C0[r]) - (HC);                                  \
            bool g0 = s0 > best[0][r];                                          \
            second[0][r] = __builtin_amdgcn_fmed3f(s0, best[0][r], second[0][r]);\
            best[0][r] = g0 ? s0 : best[0][r];                                  \
            bidx[0][r] = g0 ? n : bidx[0][r];                                   \
            float s1 = (H1[r] + C1[r]) - (HC);                                  \
            bool g1 = s1 > best[1][r];                                          \
            second[1][r] = __builtin_amdgcn_fmed3f(s1, best[1][r], second[1][r]);\
            best[1][r] = g1 ? s1 : best[1][r];                                  \
            bidx[1][r] = g1 ? n : bidx[1][r];                                   \
        }                                                                       \
    }

    for (int ct = 0; ct < NCODES / 16; ct += 2) {
        // ---- tile ct from buffer 0 ----
        f32x4 h0 = {0.f, 0.f, 0.f, 0.f}, h1 = {0.f, 0.f, 0.f, 0.f};
        f32x4 c0 = {0.f, 0.f, 0.f, 0.f}, c1 = {0.f, 0.f, 0.f, 0.f};
        MFMA(h0, ah[0][0], b0h0); MFMA(h1, ah[1][0], b0h0);
        MFMA(c0, ah[0][0], b0l0); MFMA(c1, ah[1][0], b0l0);
        MFMA(h0, ah[0][1], b0h1); MFMA(h1, ah[1][1], b0h1);
        MFMA(c0, ah[0][1], b0l1); MFMA(c1, ah[1][1], b0l1);
        MFMA(c0, al[0][0], b0h0); MFMA(c1, al[1][0], b0h0);
        MFMA(c0, al[0][1], b0h1); MFMA(c1, al[1][1], b0h1);
        float hcur0 = hc0;
        {   // prefetch tile ct+2 into buffer 0 (wraps harmlessly at the end)
            int tn = (ct + 2) & 63;
            const short* pc = baseCh + (size_t)tn * 1024;
            const short* pl = baseCl + (size_t)tn * 1024;
            b0h0 = *(const bf16x8*)pc;
            b0h1 = *(const bf16x8*)(pc + 32);
            b0l0 = *(const bf16x8*)pl;
            b0l1 = *(const bf16x8*)(pl + 32);
            hc0 = hcsq[tn * 16 + m];
        }
        EPILOGUE(h0, c0, h1, c1, hcur0, ct)

        // ---- tile ct+1 from buffer 1 ----
        f32x4 g0 = {0.f, 0.f, 0.f, 0.f}, g1 = {0.f, 0.f, 0.f, 0.f};
        f32x4 d0 = {0.f, 0.f, 0.f, 0.f}, d1 = {0.f, 0.f, 0.f, 0.f};
        MFMA(g0, ah[0][0], b1h0); MFMA(g1, ah[1][0], b1h0);
        MFMA(d0, ah[0][0], b1l0); MFMA(d1, ah[1][0], b1l0);
        MFMA(g0, ah[0][1], b1h1); MFMA(g1, ah[1][1], b1h1);
        MFMA(d0, ah[0][1], b1l1); MFMA(d1, ah[1][1], b1l1);
        MFMA(d0, al[0][0], b1h0); MFMA(d1, al[1][0], b1h0);
        MFMA(d0, al[0][1], b1h1); MFMA(d1, al[1][1], b1h1);
        float hcur1 = hc1;
        {   // prefetch tile ct+3 into buffer 1
            int tn = (ct + 3) & 63;
            const short* pc = baseCh + (size_t)tn * 1024;
            const short* pl = baseCl + (size_t)tn * 1024;
            b1h0 = *(const bf16x8*)pc;
            b1h1 = *(const bf16x8*)(pc + 32);
            b1l0 = *(const bf16x8*)pl;
            b1l1 = *(const bf16x8*)(pl + 32);
            hc1 = hcsq[tn * 16 + m];
        }
        EPILOGUE(g0, d0, g1, d1, hcur1, ct + 1)
    }
#undef EPILOGUE

    // Cross-lane top-2 merge (16-lane groups), min-index tie-break; gather,
    // write, flag near-ties for exact rescue.
#pragma unroll
    for (int t = 0; t < 2; ++t)
#pragma unroll
        for (int r = 0; r < 4; ++r) {
            float b = best[t][r], sc = second[t][r];
            int bi = bidx[t][r];
#pragma unroll
            for (int off = 1; off < 16; off <<= 1) {
                float ob = __shfl_xor(b, off);
                float os = __shfl_xor(sc, off);
                int oi = __shfl_xor(bi, off);
                sc = fmaxf(fmaxf(sc, os), fminf(b, ob));
                if (ob > b || (ob == b && oi < bi)) { b = ob; bi = oi; }
            }
            size_t row = rowbase + t * 16 + q * 4 + r;
            const float4* src = (const float4*)(cb + (size_t)bi * DIM);
            float4* dst = (float4*)(out + row * DIM);
            dst[m] = src[m];
            if (m == 0 && (b - sc) < MARGIN) {
                unsigned pos = atomicAdd(cnt, 1u);
                if (pos < LIST_CAP) list[pos] = (unsigned)row;
            }
        }
}

// ---------------------------------------------------------------------------
// Rescue: exact fp32 re-solve for flagged rows, coalesced codebook reads.
// One wave per row; lane = (code-sub g = lane>>4, dim-quad sub = lane&15):
// each float4 load is byte-linear in lane -> 1 KiB coalesced per instruction.
// ---------------------------------------------------------------------------
__global__ __launch_bounds__(256) void vq_rescue(const float* __restrict__ inputs,
                                                 const float* __restrict__ cb,
                                                 const float* __restrict__ hcsq,
                                                 const unsigned* __restrict__ cnt,
                                                 const unsigned* __restrict__ list,
                                                 float* __restrict__ out) {
    unsigned n = *cnt;
    if (n > LIST_CAP) n = LIST_CAP;
    const int lane = threadIdx.x & 63;
    const int sub = lane & 15;  // dim quad
    const int g = lane >> 4;    // code within 4-group
    unsigned gw = blockIdx.x * 4u + (threadIdx.x >> 6);
    unsigned stride = gridDim.x * 4u;
    for (unsigned e = gw; e < n; e += stride) {
        unsigned row = list[e];
        float4 xv = ((const float4*)(inputs + (size_t)row * DIM))[sub];
        float best = -INFINITY;
        int bi = 0;
#pragma unroll 2
        for (int c4 = 0; c4 < NCODES / 4; ++c4) {
            int c = c4 * 4 + g;
            float4 cv = ((const float4*)(cb + (size_t)c * DIM))[sub];
            float p = xv.x * cv.x + xv.y * cv.y + xv.z * cv.z + xv.w * cv.w;
            p += __shfl_xor(p, 1);
            p += __shfl_xor(p, 2);
            p += __shfl_xor(p, 4);
            p += __shfl_xor(p, 8);
            float s = p - hcsq[c];
            if (s > best) { best = s; bi = c; }
        }
#pragma unroll
        for (int off = 16; off < 64; off <<= 1) {
            float ob = __shfl_xor(best, off);
            int oi = __shfl_xor(bi, off);
            if (ob > best || (ob == best && oi < bi)) { best = ob; bi = oi; }
        }
        out[(size_t)row * DIM + lane] = cb[(size_t)bi * DIM + lane];
    }
}

extern "C" void kernel_launch(void* const* d_in, const int* in_sizes, int n_in,
                              void* d_out, int out_size, void* d_ws, size_t ws_size,
                              hipStream_t stream) {
    const float* inputs = (const float*)d_in[0];    // [262144, 64] fp32
    const float* cb = (const float*)d_in[1];        // [1024, 64] fp32
    float* out = (float*)d_out;

    // ws layout: hcsq f32[1024] | Ch bf16[65536] | Cl bf16[65536] | cnt | list
    char* ws = (char*)d_ws;
    float* hcsq = (float*)ws;                                   //   4 KiB
    short* Ch = (short*)(ws + 4096);                            // 128 KiB
    short* Cl = (short*)(ws + 4096 + 131072);                   // 128 KiB
    unsigned* cnt = (unsigned*)(ws + 4096 + 262144);            // 256 B slot
    unsigned* list = (unsigned*)(ws + 4096 + 262144 + 256);     // 256 KiB

    vq_prep<<<NCODES / 256, 256, 0, stream>>>(cb, hcsq, Ch, Cl, cnt);
    vq_mfma_k<<<NROWS / 128, 256, 0, stream>>>(inputs, cb, hcsq, Ch, Cl, out, cnt, list);
    vq_rescue<<<512, 256, 0, stream>>>(inputs, cb, hcsq, cnt, list, out);
}

// Round 4
// 323.010 us; speedup vs baseline: 2.9414x; 1.7731x over previous
//
#include <hip/hip_runtime.h>

#define NROWS   262144
#define NCODES  1024
#define DIM     64
#define LIST_CAP 65536u
#define STEPS   16       // 1024 codes / 64 per step
#define TILES   4        // 16-code MFMA tiles per step
#define RSTRIDE 144      // LDS bytes per code row: 128 data + 16 pad (bank-spread)
#define BUFB    (TILES * 16 * RSTRIDE)   // 9216 B per buffer

typedef _Float16 half8 __attribute__((ext_vector_type(8)));
typedef __attribute__((ext_vector_type(4))) float f32x4;

#define MFMA16(acc, a, b) acc = __builtin_amdgcn_mfma_f32_16x16x32_f16(a, b, acc, 0, 0, 0)

// ---------------------------------------------------------------------------
// Prep (1 block, 1024 threads): fp16 codebook, exact hcsq (sequential order,
// matches r1/r3 absmax-0 formula), E = max_k ||c_k - fp16(c_k)||, zero cnt.
// ---------------------------------------------------------------------------
__global__ __launch_bounds__(1024) void vq_prep(const float* __restrict__ cb,
                                                float* __restrict__ hcsq,
                                                _Float16* __restrict__ Ch,
                                                float* __restrict__ Eout,
                                                unsigned* __restrict__ cnt) {
    __shared__ float red[1024];
    const int k = threadIdx.x;
    if (k == 0) *cnt = 0u;
    const float* row = cb + (size_t)k * DIM;
    _Float16* co = Ch + (size_t)k * DIM;
    float s = 0.f, r2 = 0.f;
#pragma unroll
    for (int j = 0; j < DIM; ++j) {
        float c = row[j];
        s += c * c;                      // sequential order 0..63 (exactness-validated)
        _Float16 h = (_Float16)c;        // RNE
        co[j] = h;
        float d = c - (float)h;
        r2 += d * d;
    }
    hcsq[k] = 0.5f * s;
    red[k] = r2;
    __syncthreads();
    for (int off = 512; off > 0; off >>= 1) {
        if (k < off) red[k] = fmaxf(red[k], red[k + off]);
        __syncthreads();
    }
    if (k == 0) *Eout = sqrtf(red[0]) * 1.001f;   // pad for reduction rounding
}

// ---------------------------------------------------------------------------
// Main: fp16 2-term scores, LDS-staged codebook (block-shared, double-buffered,
// padded rows -> <=2-way banks), fused top-2 + per-row rigorous margin flag.
// Block = 256 thr = 4 waves = 128 rows; wave = 32 rows (2 m-tiles).
// ---------------------------------------------------------------------------
__global__ __launch_bounds__(256) void vq_main(const float* __restrict__ inputs,
                                               const float* __restrict__ cb,
                                               const float* __restrict__ hcsq,
                                               const _Float16* __restrict__ Ch,
                                               const float* __restrict__ Ep,
                                               float* __restrict__ out,
                                               unsigned* __restrict__ cnt,
                                               unsigned* __restrict__ list) {
    __shared__ __align__(16) char lds[2 * BUFB];
    __shared__ float shc[NCODES];
    const int tid = threadIdx.x;
    const int lane = tid & 63;
    const int wave = tid >> 6;
    const int m = lane & 15;   // A row-in-tile / B code-in-tile / D col
    const int q = lane >> 4;   // k-quad
    const size_t rowbase = (size_t)blockIdx.x * 128 + (size_t)wave * 32;

    // hcsq -> LDS (broadcast-read later, conflict-free)
    for (int i = tid; i < NCODES; i += 256) shc[i] = hcsq[i];

    // A fragments (fp16 hi+lo of x) + exact row sum-of-squares for the margin.
    half8 xh[2][2], xl[2][2];
    float xsq[2];
#pragma unroll
    for (int t = 0; t < 2; ++t) {
        const float* px = inputs + (rowbase + t * 16 + m) * DIM;
        float acc = 0.f;
#pragma unroll
        for (int s = 0; s < 2; ++s) {
            const float4* p = (const float4*)(px + q * 8 + s * 32);
            float4 v0 = p[0], v1 = p[1];
            float v[8] = {v0.x, v0.y, v0.z, v0.w, v1.x, v1.y, v1.z, v1.w};
            union { half8 f; _Float16 e[8]; } uh, ul;
#pragma unroll
            for (int j = 0; j < 8; ++j) {
                acc += v[j] * v[j];
                _Float16 h = (_Float16)v[j];
                uh.e[j] = h;
                ul.e[j] = (_Float16)(v[j] - (float)h);
            }
            xh[t][s] = uh.f;
            xl[t][s] = ul.f;
        }
        acc += __shfl_xor(acc, 16);   // reduce across k-quads (same m)
        acc += __shfl_xor(acc, 32);
        xsq[t] = acc;
    }
    const float E = Ep[0];

    float best[2][4], second[2][4];
    int bidx[2][4];
#pragma unroll
    for (int t = 0; t < 2; ++t)
#pragma unroll
        for (int r = 0; r < 4; ++r) {
            best[t][r] = -INFINITY;
            second[t][r] = -INFINITY;
            bidx[t][r] = 0;
        }

    // Staging: 512 x 16B segments per step; thread handles seg tid and tid+256.
    // seg -> (tile = seg>>7, row r = (seg>>3)&15, col g = seg&7)
    const int off0 = ((tid >> 3) * RSTRIDE) + (tid & 7) * 16;            // rows 0..31
    const int off1 = (((tid + 256) >> 3) * RSTRIDE) + (tid & 7) * 16;    // rows 32..63
    char* buf0 = lds;
    char* buf1 = lds + BUFB;
    const uint4* gb = (const uint4*)Ch;   // 16B units; 512 per step

    {   // preload step 0
        uint4 a = gb[tid], b = gb[tid + 256];
        *(uint4*)(buf0 + off0) = a;
        *(uint4*)(buf0 + off1) = b;
    }
    __syncthreads();

    for (int step = 0; step < STEPS; ++step) {
        char* curb = (step & 1) ? buf1 : buf0;
        char* nxtb = (step & 1) ? buf0 : buf1;
        uint4 nv0, nv1;
        const bool more = (step + 1) < STEPS;
        if (more) {
            nv0 = gb[(step + 1) * 512 + tid];
            nv1 = gb[(step + 1) * 512 + tid + 256];
        }
#pragma unroll
        for (int t = 0; t < TILES; ++t) {
            const char* rb = curb + (t * 16 + m) * RSTRIDE + q * 16;
            half8 b0 = *(const half8*)(rb);        // k-step 0 fragment
            half8 b1 = *(const half8*)(rb + 64);   // k-step 1 fragment
            float hc = shc[step * 64 + t * 16 + m];
            f32x4 a0 = {0.f, 0.f, 0.f, 0.f}, a1 = {0.f, 0.f, 0.f, 0.f};
            MFMA16(a0, xh[0][0], b0); MFMA16(a1, xh[1][0], b0);
            MFMA16(a0, xh[0][1], b1); MFMA16(a1, xh[1][1], b1);
            MFMA16(a0, xl[0][0], b0); MFMA16(a1, xl[1][0], b0);
            MFMA16(a0, xl[0][1], b1); MFMA16(a1, xl[1][1], b1);
            int n = step * 64 + t * 16 + m;
#pragma unroll
            for (int r = 0; r < 4; ++r) {
                float s0 = a0[r] - hc;
                bool g0 = s0 > best[0][r];
                second[0][r] = __builtin_amdgcn_fmed3f(s0, best[0][r], second[0][r]);
                best[0][r] = g0 ? s0 : best[0][r];
                bidx[0][r] = g0 ? n : bidx[0][r];
                float s1 = a1[r] - hc;
                bool g1 = s1 > best[1][r];
                second[1][r] = __builtin_amdgcn_fmed3f(s1, best[1][r], second[1][r]);
                best[1][r] = g1 ? s1 : best[1][r];
                bidx[1][r] = g1 ? n : bidx[1][r];
            }
        }
        if (more) {
            *(uint4*)(nxtb + off0) = nv0;
            *(uint4*)(nxtb + off1) = nv1;
        }
        __syncthreads();
    }

    // Cross-lane top-2 merge (16-lane groups), min-index tie-break; gather,
    // write, flag near-ties (rigorous per-row margin) for exact rescue.
#pragma unroll
    for (int t = 0; t < 2; ++t)
#pragma unroll
        for (int r = 0; r < 4; ++r) {
            float b = best[t][r], sc = second[t][r];
            int bi = bidx[t][r];
#pragma unroll
            for (int off = 1; off < 16; off <<= 1) {
                float ob = __shfl_xor(b, off);
                float os = __shfl_xor(sc, off);
                int oi = __shfl_xor(bi, off);
                sc = fmaxf(fmaxf(sc, os), fminf(b, ob));
                if (ob > b || (ob == b && oi < bi)) { b = ob; bi = oi; }
            }
            size_t row = rowbase + t * 16 + q * 4 + r;
            // ||x||^2 of the reported row lives in lane (same q, m = q*4+r).
            float xs = __shfl(xsq[t], (lane & 48) | (q * 4 + r));
            float marg = 2.0f * (sqrtf(xs) * E + 1e-3f);
            const float4* src = (const float4*)(cb + (size_t)bi * DIM);
            ((float4*)(out + row * DIM))[m] = src[m];
            if (m == 0 && (b - sc) < marg) {
                unsigned pos = atomicAdd(cnt, 1u);
                if (pos < LIST_CAP) list[pos] = (unsigned)row;
            }
        }
}

// ---------------------------------------------------------------------------
// Rescue: exact fp32 re-solve for flagged rows (r3-validated, absmax 0).
// ---------------------------------------------------------------------------
__global__ __launch_bounds__(256) void vq_rescue(const float* __restrict__ inputs,
                                                 const float* __restrict__ cb,
                                                 const float* __restrict__ hcsq,
                                                 const unsigned* __restrict__ cnt,
                                                 const unsigned* __restrict__ list,
                                                 float* __restrict__ out) {
    unsigned n = *cnt;
    if (n > LIST_CAP) n = LIST_CAP;
    const int lane = threadIdx.x & 63;
    const int sub = lane & 15;  // dim quad
    const int g = lane >> 4;    // code within 4-group
    unsigned gw = blockIdx.x * 4u + (threadIdx.x >> 6);
    unsigned stride = gridDim.x * 4u;
    for (unsigned e = gw; e < n; e += stride) {
        unsigned row = list[e];
        float4 xv = ((const float4*)(inputs + (size_t)row * DIM))[sub];
        float best = -INFINITY;
        int bi = 0;
#pragma unroll 2
        for (int c4 = 0; c4 < NCODES / 4; ++c4) {
            int c = c4 * 4 + g;
            float4 cv = ((const float4*)(cb + (size_t)c * DIM))[sub];
            float p = xv.x * cv.x + xv.y * cv.y + xv.z * cv.z + xv.w * cv.w;
            p += __shfl_xor(p, 1);
            p += __shfl_xor(p, 2);
            p += __shfl_xor(p, 4);
            p += __shfl_xor(p, 8);
            float s = p - hcsq[c];
            if (s > best) { best = s; bi = c; }
        }
#pragma unroll
        for (int off = 16; off < 64; off <<= 1) {
            float ob = __shfl_xor(best, off);
            int oi = __shfl_xor(bi, off);
            if (ob > best || (ob == best && oi < bi)) { best = ob; bi = oi; }
        }
        out[(size_t)row * DIM + lane] = cb[(size_t)bi * DIM + lane];
    }
}

extern "C" void kernel_launch(void* const* d_in, const int* in_sizes, int n_in,
                              void* d_out, int out_size, void* d_ws, size_t ws_size,
                              hipStream_t stream) {
    const float* inputs = (const float*)d_in[0];    // [262144, 64] fp32
    const float* cb = (const float*)d_in[1];        // [1024, 64] fp32
    float* out = (float*)d_out;

    // ws: hcsq f32[1024] | Ch fp16[65536] | E | cnt | list u32[65536]
    char* ws = (char*)d_ws;
    float* hcsq = (float*)ws;                                   //   4 KiB
    _Float16* Ch = (_Float16*)(ws + 4096);                      // 128 KiB
    float* Eout = (float*)(ws + 4096 + 131072);
    unsigned* cnt = (unsigned*)(ws + 4096 + 131072 + 256);
    unsigned* list = (unsigned*)(ws + 4096 + 131072 + 512);     // 256 KiB

    vq_prep<<<1, 1024, 0, stream>>>(cb, hcsq, Ch, Eout, cnt);
    vq_main<<<NROWS / 128, 256, 0, stream>>>(inputs, cb, hcsq, Ch, Eout, out, cnt, list);
    vq_rescue<<<512, 256, 0, stream>>>(inputs, cb, hcsq, cnt, list, out);
}

// Round 6
// 264.878 us; speedup vs baseline: 3.5869x; 1.2195x over previous
//
#include <hip/hip_runtime.h>

#define NROWS   262144
#define NCODES  1024
#define DIM     64
#define LIST_CAP 65536u
#define STEPS   16       // 1024 codes / 64 per step
#define TILES   4        // 16-code MFMA tiles per step
#define RSTRIDE 144      // LDS bytes per code row: 128 data + 16 pad (bank-spread)
#define BUFB    (TILES * 16 * RSTRIDE)   // 9216 B per buffer

typedef _Float16 half8 __attribute__((ext_vector_type(8)));
typedef __attribute__((ext_vector_type(4))) float f32x4;

#define MFMA16(acc, a, b) acc = __builtin_amdgcn_mfma_f32_16x16x32_f16(a, b, acc, 0, 0, 0)

// ---------------------------------------------------------------------------
// Prep: 4 blocks x 256, thread = one code row. Arithmetic bit-identical to
// r4's prep (sequential single-chain sums, TRUE residual d for E), but
// parallel across blocks. ctrl[0] = max ||c - fp16(c)||^2 bits (atomicMax,
// pre-zeroed), ctrl[1] = flag counter (pre-zeroed).
// ---------------------------------------------------------------------------
__global__ __launch_bounds__(256) void vq_prep(const float* __restrict__ cb,
                                               float* __restrict__ hcsq,
                                               _Float16* __restrict__ Ch,
                                               unsigned* ctrl) {
    const int k = blockIdx.x * 256 + threadIdx.x;   // 0..1023
    const float4* row = (const float4*)(cb + (size_t)k * DIM);
    _Float16* co = Ch + (size_t)k * DIM;
    float s = 0.f, r2 = 0.f;
#pragma unroll
    for (int i = 0; i < 8; ++i) {
        float4 a = row[2 * i], b = row[2 * i + 1];
        float v[8] = {a.x, a.y, a.z, a.w, b.x, b.y, b.z, b.w};
        union { half8 f; _Float16 e[8]; } uh;
#pragma unroll
        for (int j = 0; j < 8; ++j) {
            float c = v[j];
            s += c * c;                    // sequential chain (matches r4/r1)
            _Float16 h = (_Float16)c;      // RNE
            uh.e[j] = h;
            float d = c - (float)h;        // true residual
            r2 += d * d;
        }
        *(half8*)(co + i * 8) = uh.f;
    }
    hcsq[k] = 0.5f * s;
    float w = r2;
#pragma unroll
    for (int off = 1; off < 64; off <<= 1) w = fmaxf(w, __shfl_xor(w, off));
    if ((threadIdx.x & 63) == 0) atomicMax(ctrl + 0, __float_as_uint(w));
}

// ---------------------------------------------------------------------------
// Main: r4's kernel VERBATIM (fp16 2-term, LDS double-buffered codebook,
// fused top-2, rigorous fat margin 2(||x||E + 1e-3)) — proven absmax 0.0.
// Only change: E = sqrt(ctrl[0])*1.001 computed here (same value as r4).
// Block = 256 thr = 4 waves = 128 rows.
// ---------------------------------------------------------------------------
__global__ __launch_bounds__(256) void vq_main(const float* __restrict__ inputs,
                                               const float* __restrict__ cb,
                                               const float* __restrict__ hcsq,
                                               const _Float16* __restrict__ Ch,
                                               const unsigned* ctrl,
                                               float* __restrict__ out,
                                               unsigned* cnt,
                                               unsigned* __restrict__ list) {
    __shared__ __align__(16) char lds[2 * BUFB];
    __shared__ float shc[NCODES];
    const int tid = threadIdx.x;
    const int lane = tid & 63;
    const int wave = tid >> 6;
    const int m = lane & 15;   // A row-in-tile / B code-in-tile / D col
    const int q = lane >> 4;   // k-quad
    const size_t rowbase = (size_t)blockIdx.x * 128 + (size_t)wave * 32;

    for (int i = tid; i < NCODES; i += 256) shc[i] = hcsq[i];

    const float E = sqrtf(__uint_as_float(ctrl[0])) * 1.001f;

    // A fragments (fp16 hi+lo of x) + exact row sum-of-squares for the margin.
    half8 xh[2][2], xl[2][2];
    float xsq[2];
#pragma unroll
    for (int t = 0; t < 2; ++t) {
        const float* px = inputs + (rowbase + t * 16 + m) * DIM;
        float acc = 0.f;
#pragma unroll
        for (int s = 0; s < 2; ++s) {
            const float4* p = (const float4*)(px + q * 8 + s * 32);
            float4 v0 = p[0], v1 = p[1];
            float v[8] = {v0.x, v0.y, v0.z, v0.w, v1.x, v1.y, v1.z, v1.w};
            union { half8 f; _Float16 e[8]; } uh, ul;
#pragma unroll
            for (int j = 0; j < 8; ++j) {
                acc += v[j] * v[j];
                _Float16 h = (_Float16)v[j];
                uh.e[j] = h;
                ul.e[j] = (_Float16)(v[j] - (float)h);
            }
            xh[t][s] = uh.f;
            xl[t][s] = ul.f;
        }
        acc += __shfl_xor(acc, 16);   // reduce across k-quads (same m)
        acc += __shfl_xor(acc, 32);
        xsq[t] = acc;
    }

    float best[2][4], second[2][4];
    int bidx[2][4];
#pragma unroll
    for (int t = 0; t < 2; ++t)
#pragma unroll
        for (int r = 0; r < 4; ++r) {
            best[t][r] = -INFINITY;
            second[t][r] = -INFINITY;
            bidx[t][r] = 0;
        }

    // Staging: 512 x 16B segments per step; thread handles seg tid and tid+256.
    const int off0 = ((tid >> 3) * RSTRIDE) + (tid & 7) * 16;            // rows 0..31
    const int off1 = (((tid + 256) >> 3) * RSTRIDE) + (tid & 7) * 16;    // rows 32..63
    char* buf0 = lds;
    char* buf1 = lds + BUFB;
    const uint4* gb = (const uint4*)Ch;   // 16B units; 512 per step

    {   // preload step 0
        uint4 a = gb[tid], b = gb[tid + 256];
        *(uint4*)(buf0 + off0) = a;
        *(uint4*)(buf0 + off1) = b;
    }
    __syncthreads();

    for (int step = 0; step < STEPS; ++step) {
        char* curb = (step & 1) ? buf1 : buf0;
        char* nxtb = (step & 1) ? buf0 : buf1;
        uint4 nv0, nv1;
        const bool more = (step + 1) < STEPS;
        if (more) {
            nv0 = gb[(step + 1) * 512 + tid];
            nv1 = gb[(step + 1) * 512 + tid + 256];
        }
#pragma unroll
        for (int t = 0; t < TILES; ++t) {
            const char* rb = curb + (t * 16 + m) * RSTRIDE + q * 16;
            half8 b0 = *(const half8*)(rb);        // k-step 0 fragment
            half8 b1 = *(const half8*)(rb + 64);   // k-step 1 fragment
            float hc = shc[step * 64 + t * 16 + m];
            f32x4 a0 = {0.f, 0.f, 0.f, 0.f}, a1 = {0.f, 0.f, 0.f, 0.f};
            MFMA16(a0, xh[0][0], b0); MFMA16(a1, xh[1][0], b0);
            MFMA16(a0, xh[0][1], b1); MFMA16(a1, xh[1][1], b1);
            MFMA16(a0, xl[0][0], b0); MFMA16(a1, xl[1][0], b0);
            MFMA16(a0, xl[0][1], b1); MFMA16(a1, xl[1][1], b1);
            int n = step * 64 + t * 16 + m;
#pragma unroll
            for (int r = 0; r < 4; ++r) {
                float s0 = a0[r] - hc;
                bool g0 = s0 > best[0][r];
                second[0][r] = __builtin_amdgcn_fmed3f(s0, best[0][r], second[0][r]);
                best[0][r] = g0 ? s0 : best[0][r];
                bidx[0][r] = g0 ? n : bidx[0][r];
                float s1 = a1[r] - hc;
                bool g1 = s1 > best[1][r];
                second[1][r] = __builtin_amdgcn_fmed3f(s1, best[1][r], second[1][r]);
                best[1][r] = g1 ? s1 : best[1][r];
                bidx[1][r] = g1 ? n : bidx[1][r];
            }
        }
        if (more) {
            *(uint4*)(nxtb + off0) = nv0;
            *(uint4*)(nxtb + off1) = nv1;
        }
        __syncthreads();
    }

    // Cross-lane top-2 merge (16-lane groups), min-index tie-break; gather,
    // write, flag near-ties (rigorous per-row margin) for exact rescue.
#pragma unroll
    for (int t = 0; t < 2; ++t)
#pragma unroll
        for (int r = 0; r < 4; ++r) {
            float b = best[t][r], sc = second[t][r];
            int bi = bidx[t][r];
#pragma unroll
            for (int off = 1; off < 16; off <<= 1) {
                float ob = __shfl_xor(b, off);
                float os = __shfl_xor(sc, off);
                int oi = __shfl_xor(bi, off);
                sc = fmaxf(fmaxf(sc, os), fminf(b, ob));
                if (ob > b || (ob == b && oi < bi)) { b = ob; bi = oi; }
            }
            size_t row = rowbase + t * 16 + q * 4 + r;
            float xs = __shfl(xsq[t], (lane & 48) | (q * 4 + r));
            float marg = 2.0f * (sqrtf(xs) * E + 1e-3f);
            const float4* src = (const float4*)(cb + (size_t)bi * DIM);
            ((float4*)(out + row * DIM))[m] = src[m];
            if (m == 0 && (b - sc) < marg) {
                unsigned pos = atomicAdd(cnt, 1u);
                if (pos < LIST_CAP) list[pos] = (unsigned)row;
            }
        }
}

// ---------------------------------------------------------------------------
// Rescue: exact fp32 re-solve (r3/r4-validated arithmetic, coalesced cb
// reads). Only change: unroll 8 -> 8 independent shuffle chains in flight.
// ---------------------------------------------------------------------------
__global__ __launch_bounds__(256) void vq_rescue(const float* __restrict__ inputs,
                                                 const float* __restrict__ cb,
                                                 const float* __restrict__ hcsq,
                                                 const unsigned* cnt,
                                                 const unsigned* __restrict__ list,
                                                 float* __restrict__ out) {
    unsigned n = *cnt;
    if (n > LIST_CAP) n = LIST_CAP;
    const int lane = threadIdx.x & 63;
    const int sub = lane & 15;  // dim quad
    const int g = lane >> 4;    // code within 4-group
    unsigned gw = blockIdx.x * 4u + (threadIdx.x >> 6);
    unsigned stride = gridDim.x * 4u;
    for (unsigned e = gw; e < n; e += stride) {
        unsigned row = list[e];
        float4 xv = ((const float4*)(inputs + (size_t)row * DIM))[sub];
        float best = -INFINITY;
        int bi = 0;
#pragma unroll 8
        for (int c4 = 0; c4 < NCODES / 4; ++c4) {
            int c = c4 * 4 + g;
            float4 cv = ((const float4*)(cb + (size_t)c * DIM))[sub];
            float p = xv.x * cv.x + xv.y * cv.y + xv.z * cv.z + xv.w * cv.w;
            p += __shfl_xor(p, 1);
            p += __shfl_xor(p, 2);
            p += __shfl_xor(p, 4);
            p += __shfl_xor(p, 8);
            float s = p - hcsq[c];
            if (s > best) { best = s; bi = c; }
        }
#pragma unroll
        for (int off = 16; off < 64; off <<= 1) {
            float ob = __shfl_xor(best, off);
            int oi = __shfl_xor(bi, off);
            if (ob > best || (ob == best && oi < bi)) { best = ob; bi = oi; }
        }
        out[(size_t)row * DIM + lane] = cb[(size_t)bi * DIM + lane];
    }
}

extern "C" void kernel_launch(void* const* d_in, const int* in_sizes, int n_in,
                              void* d_out, int out_size, void* d_ws, size_t ws_size,
                              hipStream_t stream) {
    const float* inputs = (const float*)d_in[0];    // [262144, 64] fp32
    const float* cb = (const float*)d_in[1];        // [1024, 64] fp32
    float* out = (float*)d_out;

    // ws: hcsq f32[1024] | Ch fp16[65536] | ctrl u32[64] | list u32[65536]
    char* ws = (char*)d_ws;
    float* hcsq = (float*)ws;                                   //   4 KiB
    _Float16* Ch = (_Float16*)(ws + 4096);                      // 128 KiB
    unsigned* ctrl = (unsigned*)(ws + 4096 + 131072);           // 256 B slot
    unsigned* list = (unsigned*)(ws + 4096 + 131072 + 256);     // 256 KiB

    hipMemsetAsync(ctrl, 0, 8, stream);     // E2max, cnt
    vq_prep<<<4, 256, 0, stream>>>(cb, hcsq, Ch, ctrl);
    vq_main<<<NROWS / 128, 256, 0, stream>>>(inputs, cb, hcsq, Ch, ctrl,
                                             out, ctrl + 1, list);
    vq_rescue<<<512, 256, 0, stream>>>(inputs, cb, hcsq, ctrl + 1, list, out);
}